// Round 1
// baseline (190.059 us; speedup 1.0000x reference)
//
#include <hip/hip_runtime.h>

#define N_NODES   50000
#define N_EDGES   800000
#define IN_DIM    100
#define HIDDEN    16
#define N_CLASSES 40

// y1 = X @ W1   [N,100] @ [100,16] -> [N,16]
// Each block: 16 rows of X staged in LDS (contiguous 1600-float coalesced load)
// + all of W1 in LDS. Thread (r,j) computes one output element.
__global__ __launch_bounds__(256) void gemm_xw1(const float* __restrict__ X,
                                                const float* __restrict__ W,
                                                float* __restrict__ Y) {
    __shared__ float sX[16 * IN_DIM];      // 6.4 KB
    __shared__ float sW[IN_DIM * HIDDEN];  // 6.4 KB
    const int tid  = threadIdx.x;
    const int row0 = blockIdx.x * 16;

    for (int i = tid; i < IN_DIM * HIDDEN; i += 256) sW[i] = W[i];
    const float* xbase = X + (size_t)row0 * IN_DIM;
    for (int i = tid; i < 16 * IN_DIM; i += 256) sX[i] = xbase[i];
    __syncthreads();

    const int r = tid >> 4, j = tid & 15;
    float acc = 0.f;
#pragma unroll
    for (int k = 0; k < IN_DIM; ++k)
        acc = fmaf(sX[r * IN_DIM + k], sW[k * HIDDEN + j], acc);
    Y[(size_t)(row0 + r) * HIDDEN + j] = acc;
}

// Z[dst] += val * (RELU? relu(X[src]) : X[src])  over 16-dim rows.
// 16 consecutive threads handle one edge; the edge's 16 atomics hit one 64B line.
template <bool RELU>
__global__ __launch_bounds__(256) void spmm16(const int* __restrict__ src,
                                              const int* __restrict__ dst,
                                              const float* __restrict__ val,
                                              const float* __restrict__ X,
                                              float* __restrict__ Z) {
    const int tid = blockIdx.x * 256 + threadIdx.x;
    const int e = tid >> 4, j = tid & 15;
    const int s = src[e];
    const int d = dst[e];
    const float v = val[e];
    float x = X[(size_t)s * HIDDEN + j];
    if (RELU) x = fmaxf(x, 0.f);
    atomicAdd(&Z[(size_t)d * HIDDEN + j], v * x);
}

// out[n] = log_softmax(Z[n] @ W2)   [16] @ [16,40] -> [40]
__global__ __launch_bounds__(256) void out_logsoftmax(const float* __restrict__ Z,
                                                      const float* __restrict__ W2,
                                                      float* __restrict__ out) {
    __shared__ float sW[HIDDEN * N_CLASSES];  // 2.56 KB
    const int tid = threadIdx.x;
    for (int i = tid; i < HIDDEN * N_CLASSES; i += 256) sW[i] = W2[i];
    __syncthreads();

    const int n = blockIdx.x * 256 + tid;
    if (n >= N_NODES) return;

    float z[HIDDEN];
    const float4* zp = (const float4*)(Z + (size_t)n * HIDDEN);
#pragma unroll
    for (int q = 0; q < 4; ++q) {
        float4 t = zp[q];
        z[q * 4 + 0] = t.x; z[q * 4 + 1] = t.y;
        z[q * 4 + 2] = t.z; z[q * 4 + 3] = t.w;
    }

    float o[N_CLASSES];
#pragma unroll
    for (int c = 0; c < N_CLASSES; ++c) {
        float acc = 0.f;
#pragma unroll
        for (int k = 0; k < HIDDEN; ++k)
            acc = fmaf(z[k], sW[k * N_CLASSES + c], acc);
        o[c] = acc;
    }

    float m = -INFINITY;
#pragma unroll
    for (int c = 0; c < N_CLASSES; ++c) m = fmaxf(m, o[c]);
    float s = 0.f;
#pragma unroll
    for (int c = 0; c < N_CLASSES; ++c) s += __expf(o[c] - m);
    const float lse = m + __logf(s);

    float* op = out + (size_t)n * N_CLASSES;
#pragma unroll
    for (int c = 0; c < N_CLASSES; ++c) op[c] = o[c] - lse;
}

extern "C" void kernel_launch(void* const* d_in, const int* in_sizes, int n_in,
                              void* d_out, int out_size, void* d_ws, size_t ws_size,
                              hipStream_t stream) {
    const float* features = (const float*)d_in[0];  // [50000,100]
    const int*   edge_src = (const int*)d_in[1];    // [800000]
    const int*   edge_dst = (const int*)d_in[2];    // [800000]
    const float* edge_val = (const float*)d_in[3];  // [800000]
    const float* W1       = (const float*)d_in[4];  // [100,16]
    const float* W2       = (const float*)d_in[5];  // [16,40]
    float*       out      = (float*)d_out;          // [50000,40]

    const size_t HN = (size_t)N_NODES * HIDDEN;     // 800000 floats
    float* bufA = (float*)d_ws;                     // y1, later reused as z2
    float* z1   = bufA + HN;

    // y1 = X @ W1
    gemm_xw1<<<N_NODES / 16, 256, 0, stream>>>(features, W1, bufA);

    // z1 = A @ y1
    hipMemsetAsync(z1, 0, HN * sizeof(float), stream);
    spmm16<false><<<(N_EDGES * HIDDEN) / 256, 256, 0, stream>>>(
        edge_src, edge_dst, edge_val, bufA, z1);

    // z2 = A @ relu(z1)   (z2 reuses bufA; memset ordered after spmm1 on stream)
    hipMemsetAsync(bufA, 0, HN * sizeof(float), stream);
    spmm16<true><<<(N_EDGES * HIDDEN) / 256, 256, 0, stream>>>(
        edge_src, edge_dst, edge_val, z1, bufA);

    // out = log_softmax(z2 @ W2)
    out_logsoftmax<<<(N_NODES + 255) / 256, 256, 0, stream>>>(bufA, W2, out);
}